// Round 15
// baseline (55.419 us; speedup 1.0000x reference)
//
#include <hip/hip_runtime.h>
#include <hip/hip_cooperative_groups.h>

namespace cg = cooperative_groups;

#define D_MAX   50
#define T_DIM   51
#define B_DIM   16
#define P_DIM   2048
#define Q_DIM   2048
#define TSTRIDE 80            // bytes per t-row: 64 used (16 b * u32 pair) + 16 skew
#define PBY     4112          // LDS bytes per p-row (4080 + pad)
#define PSPAN   32            // p's per block
#define NPBLK   (P_DIM / PSPAN)        // 64
#define QB      512
#define PCHK    8             // W/DR pipeline chunk (4 chunks of 8 p)

// ws layout: partial ushort(bf16) [NPBLK][B][Q] = 4 MiB

// d = taps.lo*cw.lo + taps.hi*cw.hi + acc   (bf16 pair dot, f32 accumulate)
__device__ __forceinline__ float dot2bf(unsigned taps, unsigned cw, float acc) {
    float d;
    asm("v_dot2_f32_bf16 %0, %1, %2, %3" : "=v"(d) : "v"(taps), "v"(cw), "v"(acc));
    return d;
}
__device__ __forceinline__ unsigned pack_bf16x2(float lo, float hi) {
    unsigned r;
    asm("v_cvt_pk_bf16_f32 %0, %1, %2" : "=v"(r) : "v"(lo), "v"(hi));
    return r;
}
__device__ __forceinline__ unsigned short rne_bf16(float v) {
    unsigned x = __float_as_uint(v);
    x += 0x7fffu + ((x >> 16) & 1u);
    return (unsigned short)(x >> 16);
}

#define PREFETCH(wArr, xArr, cc)                                            \
    _Pragma("unroll")                                                       \
    for (int j = 0; j < PCHK; ++j) {                                        \
        wArr[j] = Wq[(size_t)(p0 + (cc) * PCHK + j) * Q_DIM];               \
        xArr[j] = Dq[(size_t)(p0 + (cc) * PCHK + j) * Q_DIM];               \
    }

#define COMPUTE8(wArr, xArr, cc)                                            \
    _Pragma("unroll")                                                       \
    for (int jj = 0; jj < PCHK; ++jj) {                                     \
        const int p = (cc) * PCHK + jj;                                     \
        const float w = wArr[jj], x = xArr[jj];                             \
        const float d = 50.f / (1.f + __expf(-x));                          \
        const int df = min((int)d, D_MAX);                                  \
        const float a  = d - (float)df;                                     \
        const float wa = w * a;                                             \
        const unsigned cw = pack_bf16x2(w - wa, wa);                        \
        const char* rb = lds + p * PBY + df * TSTRIDE;                      \
        const uint4 u0 = *(const uint4*)(rb);                               \
        const uint4 u1 = *(const uint4*)(rb + 16);                          \
        const uint4 u2 = *(const uint4*)(rb + 32);                          \
        const uint4 u3 = *(const uint4*)(rb + 48);                          \
        acc[0]  = dot2bf(u0.x, cw, acc[0]);                                 \
        acc[1]  = dot2bf(u0.y, cw, acc[1]);                                 \
        acc[2]  = dot2bf(u0.z, cw, acc[2]);                                 \
        acc[3]  = dot2bf(u0.w, cw, acc[3]);                                 \
        acc[4]  = dot2bf(u1.x, cw, acc[4]);                                 \
        acc[5]  = dot2bf(u1.y, cw, acc[5]);                                 \
        acc[6]  = dot2bf(u1.z, cw, acc[6]);                                 \
        acc[7]  = dot2bf(u1.w, cw, acc[7]);                                 \
        acc[8]  = dot2bf(u2.x, cw, acc[8]);                                 \
        acc[9]  = dot2bf(u2.y, cw, acc[9]);                                 \
        acc[10] = dot2bf(u2.z, cw, acc[10]);                                \
        acc[11] = dot2bf(u2.w, cw, acc[11]);                                \
        acc[12] = dot2bf(u3.x, cw, acc[12]);                                \
        acc[13] = dot2bf(u3.y, cw, acc[13]);                                \
        acc[14] = dot2bf(u3.z, cw, acc[14]);                                \
        acc[15] = dot2bf(u3.w, cw, acc[15]);                                \
    }

// Fused kernel (R13 body verbatim + cooperative in-kernel reduce):
// block = 512 q-lanes, 32 p. Phase 1: pack bf16 tap-pair image into LDS.
// Phase 2: 4 chunks of 8 p, W/DR register-double-buffered; per p: sigmoid
// once, 4 ds_read_b128, 16 v_dot2. Then grid.sync() and block i reduces
// outputs [128*i, 128*i+128) from the bf16 partials (LDS-combined).
__global__ __launch_bounds__(512, 2) void dsl_fused_kernel(
    const float* __restrict__ buf, const float* __restrict__ W,
    const float* __restrict__ DR, unsigned short* __restrict__ partial,
    float* __restrict__ out) {
    __shared__ char lds[PSPAN * PBY];   // 131,584 B
    const int tid = threadIdx.x;
    // 256 blocks = 4 q-cols x 64 p-slices; the 4 blocks of one p-slice are
    // 64 apart in dispatch order -> same XCD (64 % 8 == 0) -> shared L2 buf.
    const int i  = blockIdx.x;
    const int xq = i >> 6;                            // 0..3 q-column
    const int yp = ((i & 7) << 3) | ((i >> 3) & 7);   // bijective on [0,64)
    const int q  = xq * QB + tid;
    const int p0 = yp * PSPAN;

    // ---- phase 1: pack. thread = (b = tid>>5, p = tid&31)
    {
        const int bb = tid >> 5, pl = tid & 31;
        const float* src = buf + (size_t)bb * (T_DIM * P_DIM) + p0 + pl;
        float v[T_DIM + 1];
#pragma unroll
        for (int t = 0; t < T_DIM; ++t)
            v[t] = src[(size_t)t * P_DIM];    // 2 x 128B segments per t per wave
        v[T_DIM] = 0.f;
        char* wb = lds + pl * PBY + bb * 4;
#pragma unroll
        for (int t = 0; t < T_DIM; ++t)       // row t holds (v[t], v[t+1])
            *(unsigned*)(wb + t * TSTRIDE) = pack_bf16x2(v[t], v[t + 1]);
    }

    // ---- chunk-0 W/DR preload only (rest pipelined inside compute)
    const float* Wq = W + q;
    const float* Dq = DR + q;
    float wA[PCHK], xA[PCHK], wB[PCHK], xB[PCHK];
    PREFETCH(wA, xA, 0)
    __syncthreads();

    // ---- phase 2: compute, register-double-buffered W/DR stream
    float acc[B_DIM];
#pragma unroll
    for (int b = 0; b < B_DIM; ++b) acc[b] = 0.f;

    PREFETCH(wB, xB, 1)       // chunk-1 loads fly during chunk-0 compute
    COMPUTE8(wA, xA, 0)
    PREFETCH(wA, xA, 2)
    COMPUTE8(wB, xB, 1)
    PREFETCH(wB, xB, 3)
    COMPUTE8(wA, xA, 2)
    COMPUTE8(wB, xB, 3)

    unsigned short* dst = partial + (size_t)yp * (B_DIM * Q_DIM) + q;
#pragma unroll
    for (int b = 0; b < B_DIM; ++b)
        dst[(size_t)b * Q_DIM] = rne_bf16(acc[b]);    // coalesced along q

    // ---- grid-wide sync, then distributed reduce (128 outputs per block)
    cg::this_grid().sync();

    const int o0 = i * 128;                 // 256 blocks x 128 = 32768 outputs
    const int oo = tid & 127, cgi = tid >> 7;         // 4 c-groups of 16 slices
    float s = 0.f;
#pragma unroll 4
    for (int c = cgi; c < NPBLK; c += 4) {
        const unsigned u = partial[(size_t)c * (B_DIM * Q_DIM) + o0 + oo];
        s += __uint_as_float(u << 16);
    }
    float* red = (float*)lds;               // taps no longer needed (grid.sync
    red[cgi * 128 + oo] = s;                //  implies all block reads done)
    __syncthreads();
    if (tid < 128)
        out[o0 + tid] = red[tid] + red[128 + tid] + red[256 + tid] + red[384 + tid];
}

extern "C" void kernel_launch(void* const* d_in, const int* in_sizes, int n_in,
                              void* d_out, int out_size, void* d_ws, size_t ws_size,
                              hipStream_t stream) {
    const float* buf = (const float*)d_in[0];   // [B, T, P]
    const float* W   = (const float*)d_in[1];   // [P, Q]
    const float* DR  = (const float*)d_in[2];   // [P, Q]
    float* out = (float*)d_out;                 // [B, Q]

    unsigned short* partial = (unsigned short*)d_ws;  // [NPBLK][B][Q], 4 MiB

    void* args[] = {(void*)&buf, (void*)&W, (void*)&DR, (void*)&partial, (void*)&out};
    hipLaunchCooperativeKernel((const void*)dsl_fused_kernel, dim3(256), dim3(512),
                               args, 0, stream);
}

// Round 16
// 22.452 us; speedup vs baseline: 2.4684x; 2.4684x over previous
//
#include <hip/hip_runtime.h>

#define D_MAX   50
#define T_DIM   51
#define B_DIM   16
#define P_DIM   2048
#define Q_DIM   2048
#define TSTRIDE 80            // bytes per t-row: 64 used (16 b * u32 pair) + 16 skew
#define PBY     4112          // LDS bytes per p-row (4080 + pad)
#define PSPAN   32            // p's per block
#define NPBLK   (P_DIM / PSPAN)        // 64
#define QB      512
#define PCHK    8             // W/DR pipeline chunk (4 chunks of 8 p)

// ws layout: partial ushort(bf16) [NPBLK][B][Q] = 4 MiB

// d = taps.lo*cw.lo + taps.hi*cw.hi + acc   (bf16 pair dot, f32 accumulate)
__device__ __forceinline__ float dot2bf(unsigned taps, unsigned cw, float acc) {
    float d;
    asm("v_dot2_f32_bf16 %0, %1, %2, %3" : "=v"(d) : "v"(taps), "v"(cw), "v"(acc));
    return d;
}
__device__ __forceinline__ unsigned pack_bf16x2(float lo, float hi) {
    unsigned r;
    asm("v_cvt_pk_bf16_f32 %0, %1, %2" : "=v"(r) : "v"(lo), "v"(hi));
    return r;
}
__device__ __forceinline__ unsigned short rne_bf16(float v) {
    unsigned x = __float_as_uint(v);
    x += 0x7fffu + ((x >> 16) & 1u);
    return (unsigned short)(x >> 16);
}

#define PREFETCH(wArr, xArr, cc)                                            \
    _Pragma("unroll")                                                       \
    for (int j = 0; j < PCHK; ++j) {                                        \
        wArr[j] = Wq[(size_t)(p0 + (cc) * PCHK + j) * Q_DIM];               \
        xArr[j] = Dq[(size_t)(p0 + (cc) * PCHK + j) * Q_DIM];               \
    }

#define COMPUTE8(wArr, xArr, cc)                                            \
    _Pragma("unroll")                                                       \
    for (int jj = 0; jj < PCHK; ++jj) {                                     \
        const int p = (cc) * PCHK + jj;                                     \
        const float w = wArr[jj], x = xArr[jj];                             \
        const float d = 50.f / (1.f + __expf(-x));                          \
        const int df = min((int)d, D_MAX);                                  \
        const float a  = d - (float)df;                                     \
        const float wa = w * a;                                             \
        const unsigned cw = pack_bf16x2(w - wa, wa);                        \
        const char* rb = lds + p * PBY + df * TSTRIDE;                      \
        const uint4 u0 = *(const uint4*)(rb);                               \
        const uint4 u1 = *(const uint4*)(rb + 16);                          \
        const uint4 u2 = *(const uint4*)(rb + 32);                          \
        const uint4 u3 = *(const uint4*)(rb + 48);                          \
        acc[0]  = dot2bf(u0.x, cw, acc[0]);                                 \
        acc[1]  = dot2bf(u0.y, cw, acc[1]);                                 \
        acc[2]  = dot2bf(u0.z, cw, acc[2]);                                 \
        acc[3]  = dot2bf(u0.w, cw, acc[3]);                                 \
        acc[4]  = dot2bf(u1.x, cw, acc[4]);                                 \
        acc[5]  = dot2bf(u1.y, cw, acc[5]);                                 \
        acc[6]  = dot2bf(u1.z, cw, acc[6]);                                 \
        acc[7]  = dot2bf(u1.w, cw, acc[7]);                                 \
        acc[8]  = dot2bf(u2.x, cw, acc[8]);                                 \
        acc[9]  = dot2bf(u2.y, cw, acc[9]);                                 \
        acc[10] = dot2bf(u2.z, cw, acc[10]);                                \
        acc[11] = dot2bf(u2.w, cw, acc[11]);                                \
        acc[12] = dot2bf(u3.x, cw, acc[12]);                                \
        acc[13] = dot2bf(u3.y, cw, acc[13]);                                \
        acc[14] = dot2bf(u3.z, cw, acc[14]);                                \
        acc[15] = dot2bf(u3.w, cw, acc[15]);                                \
    }

// Fused kernel (R13 + 2-deep W/DR prefetch): block = 512 q-lanes, 32 p.
// Phase 1: pack bf16 tap-pair image from buf into LDS (thread=(b,p) owns a
// t-run). Phase 2: 4 chunks of 8 p; triple-buffered W/DR registers keep
// every chunk's loads >=2 compute-phases (~800 cy) ahead of their use; per
// p: sigmoid once, 4 ds_read_b128, 16 v_dot2. Epilogue: bf16 partials.
__global__ __launch_bounds__(512, 2) void dsl_fused_kernel(
    const float* __restrict__ buf, const float* __restrict__ W,
    const float* __restrict__ DR, unsigned short* __restrict__ partial) {
    __shared__ char lds[PSPAN * PBY];   // 131,584 B
    const int tid = threadIdx.x;
    // 256 blocks = 4 q-cols x 64 p-slices; the 4 blocks of one p-slice are
    // 64 apart in dispatch order -> same XCD (64 % 8 == 0) -> shared L2 buf.
    const int i  = blockIdx.x;
    const int xq = i >> 6;                            // 0..3 q-column
    const int yp = ((i & 7) << 3) | ((i >> 3) & 7);   // bijective on [0,64)
    const int q  = xq * QB + tid;
    const int p0 = yp * PSPAN;

    // ---- phase 1: pack. thread = (b = tid>>5, p = tid&31)
    {
        const int bb = tid >> 5, pl = tid & 31;
        const float* src = buf + (size_t)bb * (T_DIM * P_DIM) + p0 + pl;
        float v[T_DIM + 1];
#pragma unroll
        for (int t = 0; t < T_DIM; ++t)
            v[t] = src[(size_t)t * P_DIM];    // 2 x 128B segments per t per wave
        v[T_DIM] = 0.f;
        char* wb = lds + pl * PBY + bb * 4;
#pragma unroll
        for (int t = 0; t < T_DIM; ++t)       // row t holds (v[t], v[t+1])
            *(unsigned*)(wb + t * TSTRIDE) = pack_bf16x2(v[t], v[t + 1]);
    }

    // ---- chunk-0 W/DR preload (chunks 1,2 issued right after the barrier)
    const float* Wq = W + q;
    const float* Dq = DR + q;
    float wA[PCHK], xA[PCHK], wB[PCHK], xB[PCHK], wC[PCHK], xC[PCHK];
    PREFETCH(wA, xA, 0)
    __syncthreads();

    // ---- phase 2: compute, 2-deep register-buffered W/DR stream
    float acc[B_DIM];
#pragma unroll
    for (int b = 0; b < B_DIM; ++b) acc[b] = 0.f;

    PREFETCH(wB, xB, 1)       // in flight during chunk-0 compute
    PREFETCH(wC, xC, 2)       // in flight during chunk-0/1 compute
    COMPUTE8(wA, xA, 0)
    PREFETCH(wA, xA, 3)       // A regs free after chunk-0; 2 phases ahead
    COMPUTE8(wB, xB, 1)
    COMPUTE8(wC, xC, 2)
    COMPUTE8(wA, xA, 3)

    unsigned short* dst = partial + (size_t)yp * (B_DIM * Q_DIM) + q;
#pragma unroll
    for (int b = 0; b < B_DIM; ++b)
        dst[(size_t)b * Q_DIM] = rne_bf16(acc[b]);    // coalesced along q
}

// Reduce: sum NPBLK bf16 partials in f32; block = 64 outputs x 4 c-waves.
__global__ __launch_bounds__(256) void dsl_reduce_kernel(
    const unsigned short* __restrict__ partial, float* __restrict__ out) {
    __shared__ float lds[4][64];
    const int j = threadIdx.x & 63, w = threadIdx.x >> 6;
    const int idx = blockIdx.x * 64 + j;              // idx = b*Q + q
    float s = 0.f;
    for (int c = w; c < NPBLK; c += 4) {
        const unsigned u = partial[(size_t)c * (B_DIM * Q_DIM) + idx];
        s += __uint_as_float(u << 16);
    }
    lds[w][j] = s;
    __syncthreads();
    if (w == 0)
        out[idx] = lds[0][j] + lds[1][j] + lds[2][j] + lds[3][j];
}

extern "C" void kernel_launch(void* const* d_in, const int* in_sizes, int n_in,
                              void* d_out, int out_size, void* d_ws, size_t ws_size,
                              hipStream_t stream) {
    const float* buf = (const float*)d_in[0];   // [B, T, P]
    const float* W   = (const float*)d_in[1];   // [P, Q]
    const float* DR  = (const float*)d_in[2];   // [P, Q]
    float* out = (float*)d_out;                 // [B, Q]

    unsigned short* partial = (unsigned short*)d_ws;  // [NPBLK][B][Q], 4 MiB

    hipLaunchKernelGGL(dsl_fused_kernel, dim3(256), dim3(512), 0, stream,
                       buf, W, DR, partial);
    hipLaunchKernelGGL(dsl_reduce_kernel, dim3((B_DIM * Q_DIM) / 64), dim3(256), 0, stream,
                       partial, out);
}

// Round 17
// 21.434 us; speedup vs baseline: 2.5855x; 1.0475x over previous
//
#include <hip/hip_runtime.h>

#define D_MAX   50
#define T_DIM   51
#define B_DIM   16
#define P_DIM   2048
#define Q_DIM   2048
#define TSTRIDE 80            // bytes per t-row: 64 used (16 b * u32 pair) + 16 skew
#define PBY     4112          // LDS bytes per p-row (4080 + pad)
#define PSPAN   32            // p's per block
#define NPBLK   (P_DIM / PSPAN)        // 64
#define QB      512
#define PCHK    8             // W/DR pipeline chunk (4 chunks of 8 p)

// ws layout: partial ushort(bf16) [NPBLK][B][Q] = 4 MiB

// d = taps.lo*cw.lo + taps.hi*cw.hi + acc   (bf16 pair dot, f32 accumulate)
__device__ __forceinline__ float dot2bf(unsigned taps, unsigned cw, float acc) {
    float d;
    asm("v_dot2_f32_bf16 %0, %1, %2, %3" : "=v"(d) : "v"(taps), "v"(cw), "v"(acc));
    return d;
}
__device__ __forceinline__ unsigned pack_bf16x2(float lo, float hi) {
    unsigned r;
    asm("v_cvt_pk_bf16_f32 %0, %1, %2" : "=v"(r) : "v"(lo), "v"(hi));
    return r;
}
__device__ __forceinline__ unsigned short rne_bf16(float v) {
    unsigned x = __float_as_uint(v);
    x += 0x7fffu + ((x >> 16) & 1u);
    return (unsigned short)(x >> 16);
}

#define PREFETCH(wArr, xArr, cc)                                            \
    _Pragma("unroll")                                                       \
    for (int j = 0; j < PCHK; ++j) {                                        \
        wArr[j] = Wq[(size_t)(p0 + (cc) * PCHK + j) * Q_DIM];               \
        xArr[j] = Dq[(size_t)(p0 + (cc) * PCHK + j) * Q_DIM];               \
    }

#define COMPUTE8(wArr, xArr, cc)                                            \
    _Pragma("unroll")                                                       \
    for (int jj = 0; jj < PCHK; ++jj) {                                     \
        const int p = (cc) * PCHK + jj;                                     \
        const float w = wArr[jj], x = xArr[jj];                             \
        const float d = 50.f / (1.f + __expf(-x));                          \
        const int df = min((int)d, D_MAX);                                  \
        const float a  = d - (float)df;                                     \
        const float wa = w * a;                                             \
        const unsigned cw = pack_bf16x2(w - wa, wa);                        \
        const char* rb = lds + p * PBY + df * TSTRIDE;                      \
        const uint4 u0 = *(const uint4*)(rb);                               \
        const uint4 u1 = *(const uint4*)(rb + 16);                          \
        const uint4 u2 = *(const uint4*)(rb + 32);                          \
        const uint4 u3 = *(const uint4*)(rb + 48);                          \
        acc[0]  = dot2bf(u0.x, cw, acc[0]);                                 \
        acc[1]  = dot2bf(u0.y, cw, acc[1]);                                 \
        acc[2]  = dot2bf(u0.z, cw, acc[2]);                                 \
        acc[3]  = dot2bf(u0.w, cw, acc[3]);                                 \
        acc[4]  = dot2bf(u1.x, cw, acc[4]);                                 \
        acc[5]  = dot2bf(u1.y, cw, acc[5]);                                 \
        acc[6]  = dot2bf(u1.z, cw, acc[6]);                                 \
        acc[7]  = dot2bf(u1.w, cw, acc[7]);                                 \
        acc[8]  = dot2bf(u2.x, cw, acc[8]);                                 \
        acc[9]  = dot2bf(u2.y, cw, acc[9]);                                 \
        acc[10] = dot2bf(u2.z, cw, acc[10]);                                \
        acc[11] = dot2bf(u2.w, cw, acc[11]);                                \
        acc[12] = dot2bf(u3.x, cw, acc[12]);                                \
        acc[13] = dot2bf(u3.y, cw, acc[13]);                                \
        acc[14] = dot2bf(u3.z, cw, acc[14]);                                \
        acc[15] = dot2bf(u3.w, cw, acc[15]);                                \
    }

// Fused kernel (champion R13): block = 512 q-lanes, 32 p.
// Phase 1: pack bf16 tap-pair image from buf into LDS (thread=(b,p) owns a
// t-run). Phase 2: 4 chunks of 8 p; chunk c+1's W/DR loads issue during
// chunk c's compute (register double-buffer); per p: sigmoid once, 4
// ds_read_b128 (one 64B skewed row = both taps for all 16 b), 16 v_dot2.
__global__ __launch_bounds__(512, 2) void dsl_fused_kernel(
    const float* __restrict__ buf, const float* __restrict__ W,
    const float* __restrict__ DR, unsigned short* __restrict__ partial) {
    __shared__ char lds[PSPAN * PBY];   // 131,584 B
    const int tid = threadIdx.x;
    // 256 blocks = 4 q-cols x 64 p-slices; the 4 blocks of one p-slice are
    // 64 apart in dispatch order -> same XCD (64 % 8 == 0) -> shared L2 buf.
    const int i  = blockIdx.x;
    const int xq = i >> 6;                            // 0..3 q-column
    const int yp = ((i & 7) << 3) | ((i >> 3) & 7);   // bijective on [0,64)
    const int q  = xq * QB + tid;
    const int p0 = yp * PSPAN;

    // ---- phase 1: pack. thread = (b = tid>>5, p = tid&31)
    {
        const int bb = tid >> 5, pl = tid & 31;
        const float* src = buf + (size_t)bb * (T_DIM * P_DIM) + p0 + pl;
        float v[T_DIM + 1];
#pragma unroll
        for (int t = 0; t < T_DIM; ++t)
            v[t] = src[(size_t)t * P_DIM];    // 2 x 128B segments per t per wave
        v[T_DIM] = 0.f;
        char* wb = lds + pl * PBY + bb * 4;
#pragma unroll
        for (int t = 0; t < T_DIM; ++t)       // row t holds (v[t], v[t+1])
            *(unsigned*)(wb + t * TSTRIDE) = pack_bf16x2(v[t], v[t + 1]);
    }

    // ---- chunk-0 W/DR preload only (rest pipelined inside compute)
    const float* Wq = W + q;
    const float* Dq = DR + q;
    float wA[PCHK], xA[PCHK], wB[PCHK], xB[PCHK];
    PREFETCH(wA, xA, 0)
    __syncthreads();

    // ---- phase 2: compute, register-double-buffered W/DR stream
    float acc[B_DIM];
#pragma unroll
    for (int b = 0; b < B_DIM; ++b) acc[b] = 0.f;

    PREFETCH(wB, xB, 1)       // chunk-1 loads fly during chunk-0 compute
    COMPUTE8(wA, xA, 0)
    PREFETCH(wA, xA, 2)
    COMPUTE8(wB, xB, 1)
    PREFETCH(wB, xB, 3)
    COMPUTE8(wA, xA, 2)
    COMPUTE8(wB, xB, 3)

    unsigned short* dst = partial + (size_t)yp * (B_DIM * Q_DIM) + q;
#pragma unroll
    for (int b = 0; b < B_DIM; ++b)
        dst[(size_t)b * Q_DIM] = rne_bf16(acc[b]);    // coalesced along q
}

// Reduce: sum NPBLK bf16 partials in f32; block = 64 outputs x 4 c-waves.
__global__ __launch_bounds__(256) void dsl_reduce_kernel(
    const unsigned short* __restrict__ partial, float* __restrict__ out) {
    __shared__ float lds[4][64];
    const int j = threadIdx.x & 63, w = threadIdx.x >> 6;
    const int idx = blockIdx.x * 64 + j;              // idx = b*Q + q
    float s = 0.f;
    for (int c = w; c < NPBLK; c += 4) {
        const unsigned u = partial[(size_t)c * (B_DIM * Q_DIM) + idx];
        s += __uint_as_float(u << 16);
    }
    lds[w][j] = s;
    __syncthreads();
    if (w == 0)
        out[idx] = lds[0][j] + lds[1][j] + lds[2][j] + lds[3][j];
}

extern "C" void kernel_launch(void* const* d_in, const int* in_sizes, int n_in,
                              void* d_out, int out_size, void* d_ws, size_t ws_size,
                              hipStream_t stream) {
    const float* buf = (const float*)d_in[0];   // [B, T, P]
    const float* W   = (const float*)d_in[1];   // [P, Q]
    const float* DR  = (const float*)d_in[2];   // [P, Q]
    float* out = (float*)d_out;                 // [B, Q]

    unsigned short* partial = (unsigned short*)d_ws;  // [NPBLK][B][Q], 4 MiB

    hipLaunchKernelGGL(dsl_fused_kernel, dim3(256), dim3(512), 0, stream,
                       buf, W, DR, partial);
    hipLaunchKernelGGL(dsl_reduce_kernel, dim3((B_DIM * Q_DIM) / 64), dim3(256), 0, stream,
                       partial, out);
}